// Round 5
// baseline (310.828 us; speedup 1.0000x reference)
//
#include <hip/hip_runtime.h>

#define TLEN 100
#define ECN  100
#define CA1N 100
#define CA3N 100
#define BSZ  4096
#define ACTN 2
#define BT   32     // TWO independent 16-row groups per block, software-pipelined

typedef short bf16x8 __attribute__((ext_vector_type(8)));
typedef float f32x4  __attribute__((ext_vector_type(4)));

__device__ __forceinline__ unsigned short f2bf(float f){ // round-half-up bf16
  union { float f; unsigned int u; } c; c.f = f;
  return (unsigned short)((c.u + 0x8000u) >> 16);
}
__device__ __forceinline__ float fsigm(float x){ // 1/(1+exp(-x)), fast rcp
  float e = __expf(-x);
  return __builtin_amdgcn_rcpf(1.0f + e);
}

// Barrier with LDS-only drain (R2 win): correctness needs only LDS ordering
// across waves; global stores / drive loads float across it.
#define BAR_LGKM() asm volatile("s_waitcnt lgkmcnt(0)\n\ts_barrier" ::: "memory")

// ---- kernel 0: drive[t][j] = sum_k exp(-((t-c_k)/5)^2/2) * Wca3ca1[k][j] ----
__global__ void drive_kernel(const float* __restrict__ Wca3ca1, float* __restrict__ drive){
  __shared__ float ca3row[CA3N];
  const int t = blockIdx.x, tid = threadIdx.x;
  if (tid < CA3N){
    float c = (float)tid * (100.0f / 99.0f);   // linspace(0,100,100)
    float d = ((float)t - c) * 0.2f;           // /SIGMA=5
    ca3row[tid] = __expf(-0.5f * d * d);
  }
  __syncthreads();
  if (tid < CA1N){
    float acc = 0.f;
    for (int k = 0; k < CA3N; ++k) acc = fmaf(ca3row[k], Wca3ca1[k*CA1N + tid], acc);
    drive[t*CA1N + tid] = acc;
  }
}

// frag-linear bf16 A-shadow (per group): element (m,k) at
//   ks*512 + (m + 16*((k>>3)&3))*8 + (k&7)  [shorts], ks=k>>5.
//
// R5 pipeline: G0/G1 phase-shifted by half a step. Each barrier region holds
// two INDEPENDENT phase-units on disjoint LDS buffers:
//   region A(t): ph1(G1,t)  ∥ ph2(G0,t)    [reads ec3b·G1, ca1b·G0 ;
//                                           writes ca1b·G1, ec3b·G0]
//   region B(t): ph1(G0,t+1) ∥ ph2(G1,t)   [reads ec3b·G0, ca1b·G1 ;
//                                           writes ca1b·G0, ec3b·G1]
// -> one unit's ds_read/MFMA/exp chain overlaps the other's issue (R2's
// regions had zero internal ILP; serial accounting matched its 2740cy/step).

__global__ __launch_bounds__(512, 2)
void rnn_kernel(const int*   __restrict__ cue_train,
                const float* __restrict__ ec3_last,
                const float* __restrict__ ec5_last,
                const float* __restrict__ cueL,
                const float* __restrict__ cueR,
                const float* __restrict__ Wec3ca1,
                const float* __restrict__ Wca1ec5,
                const float* __restrict__ Wca1act,
                const float* __restrict__ ca1bias,
                const float* __restrict__ drive,
                float*       __restrict__ out)
{
  __shared__ __align__(16) unsigned short ec3b[2 * 2048]; // [group][frag-linear]
  __shared__ __align__(16) unsigned short ca1b[2 * 2048];
  __shared__ __align__(16) float ca1f[BT * 132];          // final ca1 (epilogue)
  __shared__ signed char cueT[TLEN * BT];                 // cue transposed [t][r]

  const int tid = threadIdx.x;   // 0..511
  const int b0  = blockIdx.x * BT;

  float* out_act = out;
  float* out_his = out + (size_t)BSZ * ACTN;
  float* out_e3  = out_his + (size_t)TLEN * BSZ * CA1N;
  float* out_e5  = out_e3 + (size_t)BSZ * ECN;
  float* out_c1  = out_e5 + (size_t)BSZ * ECN;

  // --- zero frag shadows (pad rows k>=100 must stay 0 forever) ---
  for (int idx = tid; idx < 2 * 2048; idx += 512){ ec3b[idx] = 0; ca1b[idx] = 0; }
  // --- stage cue ---
  for (int idx = tid; idx < BT * TLEN; idx += 512){
    int t = idx >> 5, r = idx & 31;
    cueT[idx] = (signed char)cue_train[(size_t)(b0 + r) * TLEN + t];
  }

  const int lane  = tid & 63;
  const int wv    = tid >> 6;          // wave id = col-tile 0..7
  const int col16 = lane & 15;
  const int q     = lane >> 4;         // quad (rows q*4.. within group)
  const int col   = wv * 16 + col16;
  const bool okc  = (col < CA1N);
  const bool wactive = (wv < 7);       // tile 7: all cols dead
  const int colc  = okc ? col : 0;

  // per-lane frag base within a group's shadow (shorts)
  const int abase = (col >> 5) * 512 + ((col >> 3) & 3) * 128 + (col & 7) + q * 32;

  // --- B-fragments in registers (bf16 weights), shared by both groups ---
  bf16x8 b1[4], b2[4];                 // B[k][n]: n=lane&15, k=ks*32+q*8+jj
  #pragma unroll
  for (int ks = 0; ks < 4; ++ks){
    #pragma unroll
    for (int jj = 0; jj < 8; ++jj){
      int k = ks * 32 + q * 8 + jj;
      float w1 = 0.f, w2 = 0.f;
      if (k < ECN && okc){
        w1 = Wec3ca1[k * CA1N + col];
        w2 = Wca1ec5[k * ECN  + col];
      }
      b1[ks][jj] = (short)f2bf(w1);
      b2[ks][jj] = (short)f2bf(w2);
    }
  }
  const float bias_c = okc ? ca1bias[col] : 0.f;
  const float cL = okc ? cueL[col] : 0.f;
  const float cR = okc ? cueR[col] : 0.f;

  __syncthreads();  // frag zero complete before state writes

  // --- fp32 state in registers, per group ---
  float e3v0[4], e5v0[4], c10[4] = {0.f,0.f,0.f,0.f};
  float e3v1[4], e5v1[4], c11[4] = {0.f,0.f,0.f,0.f};
  #pragma unroll
  for (int i = 0; i < 4; ++i){
    int r0 = q * 4 + i, r1 = 16 + q * 4 + i;
    float a3 = okc ? ec3_last[(size_t)(b0 + r0) * ECN + col] : 0.f;
    float a5 = okc ? ec5_last[(size_t)(b0 + r0) * ECN + col] : 0.f;
    float g3 = okc ? ec3_last[(size_t)(b0 + r1) * ECN + col] : 0.f;
    float g5 = okc ? ec5_last[(size_t)(b0 + r1) * ECN + col] : 0.f;
    e3v0[i] = a3; e5v0[i] = a5; e3v1[i] = g3; e5v1[i] = g5;
    if (okc){
      ec3b[abase + i * 8]        = f2bf(a3);
      ec3b[2048 + abase + i * 8] = f2bf(g3);
    }
  }
  __syncthreads();

  const bf16x8* fe30 = (const bf16x8*)ec3b;
  const bf16x8* fe31 = (const bf16x8*)(ec3b + 2048);
  const bf16x8* fc10 = (const bf16x8*)ca1b;
  const bf16x8* fc11 = (const bf16x8*)(ca1b + 2048);

  const float* dp = drive + colc;
  float dva = dp[0];          // drive[t]   (regions at step t)
  float dvb = dp[CA1N];       // drive[t+1] (region B's ph1(G0,t+1))
  dp += 2 * CA1N;             // next prefetch = drive[t+2]

  float* hp0 = out_his + (size_t)(b0 + q * 4) * CA1N + colc;
  float* hp1 = out_his + (size_t)(b0 + 16 + q * 4) * CA1N + colc;

  // ---- prologue: phase1(G0, t=0) ----
  if (wactive){
    bf16x8 a0 = fe30[  0 + lane], a1 = fe30[ 64 + lane];
    bf16x8 a2 = fe30[128 + lane], a3 = fe30[192 + lane];
    f32x4 aA = {0.f,0.f,0.f,0.f}, aB = {0.f,0.f,0.f,0.f};
    aA = __builtin_amdgcn_mfma_f32_16x16x32_bf16(a0, b1[0], aA, 0, 0, 0);
    aB = __builtin_amdgcn_mfma_f32_16x16x32_bf16(a1, b1[1], aB, 0, 0, 0);
    aA = __builtin_amdgcn_mfma_f32_16x16x32_bf16(a2, b1[2], aA, 0, 0, 0);
    aB = __builtin_amdgcn_mfma_f32_16x16x32_bf16(a3, b1[3], aB, 0, 0, 0);
    f32x4 z = aA + aB;
    float dmb = dva - bias_c;
    #pragma unroll
    for (int i = 0; i < 4; ++i){
      float v = fmaxf(fmaf(dva, fsigm(z[i]), dmb), 0.f);
      c10[i] = v;
      if (okc) ca1b[abase + i * 8] = f2bf(v);
    }
    if (okc){
      hp0[0 * CA1N] = c10[0]; hp0[1 * CA1N] = c10[1];
      hp0[2 * CA1N] = c10[2]; hp0[3 * CA1N] = c10[3];
    }
  }
  hp0 += (size_t)BSZ * CA1N;
  BAR_LGKM();

  for (int t = 0; t < TLEN; ++t){
    int cu40 = *(const int*)(cueT + t * BT + q * 4);        // G0 rows
    int cu41 = *(const int*)(cueT + t * BT + 16 + q * 4);   // G1 rows

    // ---- region A: phase1(G1,t) ∥ phase2(G0,t) ----
    if (wactive){
      bf16x8 e0 = fe31[  0 + lane], e1 = fe31[ 64 + lane];
      bf16x8 e2 = fe31[128 + lane], e3 = fe31[192 + lane];
      bf16x8 u0 = fc10[  0 + lane], u1 = fc10[ 64 + lane];
      bf16x8 u2 = fc10[128 + lane], u3 = fc10[192 + lane];
      f32x4 pA = {0.f,0.f,0.f,0.f}, pB = {0.f,0.f,0.f,0.f};
      f32x4 rA = {0.f,0.f,0.f,0.f}, rB = {0.f,0.f,0.f,0.f};
      pA = __builtin_amdgcn_mfma_f32_16x16x32_bf16(e0, b1[0], pA, 0, 0, 0);
      rA = __builtin_amdgcn_mfma_f32_16x16x32_bf16(u0, b2[0], rA, 0, 0, 0);
      pB = __builtin_amdgcn_mfma_f32_16x16x32_bf16(e1, b1[1], pB, 0, 0, 0);
      rB = __builtin_amdgcn_mfma_f32_16x16x32_bf16(u1, b2[1], rB, 0, 0, 0);
      pA = __builtin_amdgcn_mfma_f32_16x16x32_bf16(e2, b1[2], pA, 0, 0, 0);
      rA = __builtin_amdgcn_mfma_f32_16x16x32_bf16(u2, b2[2], rA, 0, 0, 0);
      pB = __builtin_amdgcn_mfma_f32_16x16x32_bf16(e3, b1[3], pB, 0, 0, 0);
      rB = __builtin_amdgcn_mfma_f32_16x16x32_bf16(u3, b2[3], rB, 0, 0, 0);
      f32x4 z1 = pA + pB;     // G1 phase-1 pre-activation
      f32x4 z20 = rA + rB;    // G0 phase-2 increment
      // G1 phase-1 tail
      float dmb = dva - bias_c;
      #pragma unroll
      for (int i = 0; i < 4; ++i){
        float v = fmaxf(fmaf(dva, fsigm(z1[i]), dmb), 0.f);
        c11[i] = v;
        if (okc) ca1b[2048 + abase + i * 8] = f2bf(v);
      }
      // G0 phase-2 tail
      #pragma unroll
      for (int i = 0; i < 4; ++i){
        float x  = e5v0[i] + z20[i];
        float e5 = fmaf(0.3f, fsigm(fmaf(4.0f, x, -1.2f)), 0.69f);
        e5v0[i] = e5;
        int cu = (cu40 >> (8 * i)) & 0xff;                // -1 -> 0xff
        float sns = (cu == 1) ? cL : ((cu == 0xff) ? cR : 0.0f);
        float e3n = fmaf(e5, e3v0[i], sns);
        e3v0[i] = e3n;
        if (okc) ec3b[abase + i * 8] = f2bf(e3n);
      }
      // store his(G1, t) — floats across the lgkm-only barrier
      if (okc){
        hp1[0 * CA1N] = c11[0]; hp1[1 * CA1N] = c11[1];
        hp1[2 * CA1N] = c11[2]; hp1[3 * CA1N] = c11[3];
      }
    }
    hp1 += (size_t)BSZ * CA1N;
    BAR_LGKM();

    float dnx = (t + 2 < TLEN) ? dp[0] : 0.f;
    dp += CA1N;
    const bool doG0 = (t + 1 < TLEN);   // wave-uniform

    // ---- region B: phase1(G0,t+1) ∥ phase2(G1,t) ----
    if (wactive){
      bf16x8 e0 = fe30[  0 + lane], e1 = fe30[ 64 + lane];
      bf16x8 e2 = fe30[128 + lane], e3 = fe30[192 + lane];
      bf16x8 u0 = fc11[  0 + lane], u1 = fc11[ 64 + lane];
      bf16x8 u2 = fc11[128 + lane], u3 = fc11[192 + lane];
      f32x4 pA = {0.f,0.f,0.f,0.f}, pB = {0.f,0.f,0.f,0.f};
      f32x4 rA = {0.f,0.f,0.f,0.f}, rB = {0.f,0.f,0.f,0.f};
      pA = __builtin_amdgcn_mfma_f32_16x16x32_bf16(e0, b1[0], pA, 0, 0, 0);
      rA = __builtin_amdgcn_mfma_f32_16x16x32_bf16(u0, b2[0], rA, 0, 0, 0);
      pB = __builtin_amdgcn_mfma_f32_16x16x32_bf16(e1, b1[1], pB, 0, 0, 0);
      rB = __builtin_amdgcn_mfma_f32_16x16x32_bf16(u1, b2[1], rB, 0, 0, 0);
      pA = __builtin_amdgcn_mfma_f32_16x16x32_bf16(e2, b1[2], pA, 0, 0, 0);
      rA = __builtin_amdgcn_mfma_f32_16x16x32_bf16(u2, b2[2], rA, 0, 0, 0);
      pB = __builtin_amdgcn_mfma_f32_16x16x32_bf16(e3, b1[3], pB, 0, 0, 0);
      rB = __builtin_amdgcn_mfma_f32_16x16x32_bf16(u3, b2[3], rB, 0, 0, 0);
      f32x4 z0 = pA + pB;     // G0 phase-1 pre-activation (t+1)
      f32x4 z21 = rA + rB;    // G1 phase-2 increment
      // G1 phase-2 tail (always)
      #pragma unroll
      for (int i = 0; i < 4; ++i){
        float x  = e5v1[i] + z21[i];
        float e5 = fmaf(0.3f, fsigm(fmaf(4.0f, x, -1.2f)), 0.69f);
        e5v1[i] = e5;
        int cu = (cu41 >> (8 * i)) & 0xff;
        float sns = (cu == 1) ? cL : ((cu == 0xff) ? cR : 0.0f);
        float e3n = fmaf(e5, e3v1[i], sns);
        e3v1[i] = e3n;
        if (okc) ec3b[2048 + abase + i * 8] = f2bf(e3n);
      }
      // G0 phase-1 tail (skipped at t=99: ph1(G0,100) doesn't exist)
      if (doG0){
        float dmb = dvb - bias_c;
        #pragma unroll
        for (int i = 0; i < 4; ++i){
          float v = fmaxf(fmaf(dvb, fsigm(z0[i]), dmb), 0.f);
          c10[i] = v;
          if (okc) ca1b[abase + i * 8] = f2bf(v);
        }
        if (okc){
          hp0[0 * CA1N] = c10[0]; hp0[1 * CA1N] = c10[1];
          hp0[2 * CA1N] = c10[2]; hp0[3 * CA1N] = c10[3];
        }
      }
    }
    hp0 += (size_t)BSZ * CA1N;
    BAR_LGKM();
    dva = dvb; dvb = dnx;
  }

  // ---- epilogue: dump final states from registers (both groups) ----
  if (okc){
    #pragma unroll
    for (int i = 0; i < 4; ++i){
      int r0 = q * 4 + i, r1 = 16 + q * 4 + i;
      size_t g0 = (size_t)(b0 + r0) * ECN + col;
      size_t g1 = (size_t)(b0 + r1) * ECN + col;
      out_e3[g0] = e3v0[i]; out_e5[g0] = e5v0[i]; out_c1[g0] = c10[i];
      out_e3[g1] = e3v1[i]; out_e5[g1] = e5v1[i]; out_c1[g1] = c11[i];
      ca1f[r0 * 132 + col] = c10[i];
      ca1f[r1 * 132 + col] = c11[i];
    }
  }
  __syncthreads();

  // actCell = ca1_final @ Wca1act
  if (tid < BT * ACTN){
    int r = tid >> 1, a = tid & 1;
    float acc = 0.f;
    for (int jj = 0; jj < CA1N; ++jj)
      acc = fmaf(ca1f[r * 132 + jj], Wca1act[jj * ACTN + a], acc);
    out_act[(size_t)(b0 + r) * ACTN + a] = acc;
  }
}

extern "C" void kernel_launch(void* const* d_in, const int* in_sizes, int n_in,
                              void* d_out, int out_size, void* d_ws, size_t ws_size,
                              hipStream_t stream) {
  (void)in_sizes; (void)n_in; (void)out_size; (void)ws_size;
  const int*   cue_train = (const int*)  d_in[1];
  const float* ec3_last  = (const float*)d_in[2];
  const float* ec5_last  = (const float*)d_in[3];
  const float* cueL      = (const float*)d_in[5];
  const float* cueR      = (const float*)d_in[6];
  const float* Wec3ca1   = (const float*)d_in[7];
  const float* Wca3ca1   = (const float*)d_in[8];
  const float* Wca1ec5   = (const float*)d_in[9];
  const float* Wca1act   = (const float*)d_in[10];
  const float* ca1bias   = (const float*)d_in[11];
  float* out   = (float*)d_out;
  float* drive = (float*)d_ws;   // 100*100 fp32 = 40 KB scratch

  drive_kernel<<<TLEN, 128, 0, stream>>>(Wca3ca1, drive);
  rnn_kernel<<<BSZ / BT, 512, 0, stream>>>(cue_train, ec3_last, ec5_last,
                                           cueL, cueR, Wec3ca1, Wca1ec5,
                                           Wca1act, ca1bias, drive, out);
}

// Round 7
// 261.003 us; speedup vs baseline: 1.1909x; 1.1909x over previous
//
#include <hip/hip_runtime.h>

#define TLEN 100
#define ECN  100
#define CA1N 100
#define CA3N 100
#define BSZ  4096
#define ACTN 2
#define BT   16     // batch rows per block (= MFMA M)
#define NTHR 448    // 7 waves — every wave owns a live col-tile (R6)

typedef short bf16x8 __attribute__((ext_vector_type(8)));
typedef float f32x4  __attribute__((ext_vector_type(4)));

__device__ __forceinline__ unsigned short f2bf(float f){ // round-half-up bf16
  union { float f; unsigned int u; } c; c.f = f;
  return (unsigned short)((c.u + 0x8000u) >> 16);
}
__device__ __forceinline__ float fsigm(float x){ // 1/(1+exp(-x)), fast rcp
  float e = __expf(-x);
  return __builtin_amdgcn_rcpf(1.0f + e);
}

// Barrier with LDS-only drain (R2 win, -13%): correctness needs only
// ca1b/ec3b LDS ordering across waves; global stores / drive loads float.
#define BAR_LGKM() asm volatile("s_waitcnt lgkmcnt(0)\n\ts_barrier" ::: "memory")

// ---- kernel 0: drive[t][j] = sum_k exp(-((t-c_k)/5)^2/2) * Wca3ca1[k][j] ----
__global__ void drive_kernel(const float* __restrict__ Wca3ca1, float* __restrict__ drive){
  __shared__ float ca3row[CA3N];
  const int t = blockIdx.x, tid = threadIdx.x;
  if (tid < CA3N){
    float c = (float)tid * (100.0f / 99.0f);   // linspace(0,100,100)
    float d = ((float)t - c) * 0.2f;           // /SIGMA=5
    ca3row[tid] = __expf(-0.5f * d * d);
  }
  __syncthreads();
  if (tid < CA1N){
    float acc = 0.f;
    for (int k = 0; k < CA3N; ++k) acc = fmaf(ca3row[k], Wca3ca1[k*CA1N + tid], acc);
    drive[t*CA1N + tid] = acc;
  }
}

// frag-linear bf16 A-shadow: element (m,k) lives at
//   ks*512 + (m + 16*((k>>3)&3))*8 + (k&7)   [shorts], ks = k>>5
// so a wave's ds_read_b128 at (ks*1024 + lane*16) bytes is lane-contiguous.
//
// R6 (resubmit; prior run was an infra failure, kernel never executed):
// 7 waves (448 thr). Per-region model (fit from R2/R3/R5): region = F + U*W
// with F≈365ns (barrier+latency chain), W≈205ns; 2 regions/step are
// structurally minimal (ph1->ph2 all-to-all dependency). F scales with
// barrier width (F4=270 < F8=365) -> drop the dead 8th wave.

__global__ __launch_bounds__(NTHR, 2)
void rnn_kernel(const int*   __restrict__ cue_train,
                const float* __restrict__ ec3_last,
                const float* __restrict__ ec5_last,
                const float* __restrict__ cueL,
                const float* __restrict__ cueR,
                const float* __restrict__ Wec3ca1,
                const float* __restrict__ Wca1ec5,
                const float* __restrict__ Wca1act,
                const float* __restrict__ ca1bias,
                const float* __restrict__ drive,
                float*       __restrict__ out)
{
  __shared__ __align__(16) unsigned short ec3b[4 * 64 * 8]; // frag-linear bf16 ec3
  __shared__ __align__(16) unsigned short ca1b[4 * 64 * 8]; // frag-linear bf16 ca1
  __shared__ __align__(16) float ca1f[BT * 132];            // final ca1 (epilogue)
  __shared__ signed char cueT[TLEN * BT];                   // cue transposed [t][r]

  const int tid = threadIdx.x;   // 0..447
  const int b0  = blockIdx.x * BT;

  float* out_act = out;
  float* out_his = out + (size_t)BSZ * ACTN;
  float* out_e3  = out_his + (size_t)TLEN * BSZ * CA1N;
  float* out_e5  = out_e3 + (size_t)BSZ * ECN;
  float* out_c1  = out_e5 + (size_t)BSZ * ECN;

  // --- zero frag shadows (pad rows k>=100 must stay 0 forever) ---
  for (int idx = tid; idx < 4 * 64 * 8; idx += NTHR){ ec3b[idx] = 0; ca1b[idx] = 0; }
  // --- stage cue ---
  for (int idx = tid; idx < BT * TLEN; idx += NTHR){
    int t = idx >> 4, r = idx & 15;
    cueT[idx] = (signed char)cue_train[(size_t)(b0 + r) * TLEN + t];
  }

  const int lane  = tid & 63;
  const int wv    = tid >> 6;          // wave id = N-tile id (0..6, all live)
  const int col16 = lane & 15;
  const int q     = lane >> 4;         // quad
  const int col   = wv * 16 + col16;   // output column (CA1 ph1 / EC ph2)
  const bool okc  = (col < CA1N);      // cols 100..111 dead lanes in wave 6
  const int colc  = okc ? col : 0;

  // per-lane frag-write base (shorts): same formula for ec3 (k=col) and ca1 (k=col)
  const int abase = (col >> 5) * 512 + ((col >> 3) & 3) * 128 + (col & 7) + q * 32;

  // --- B-fragments in registers (bf16 weights) ---
  bf16x8 b1[4], b2[4];                 // B[k][n]: n=lane&15, k=ks*32+q*8+jj
  #pragma unroll
  for (int ks = 0; ks < 4; ++ks){
    #pragma unroll
    for (int jj = 0; jj < 8; ++jj){
      int k = ks * 32 + q * 8 + jj;
      float w1 = 0.f, w2 = 0.f;
      if (k < ECN && okc){
        w1 = Wec3ca1[k * CA1N + col];
        w2 = Wca1ec5[k * ECN  + col];
      }
      b1[ks][jj] = (short)f2bf(w1);
      b2[ks][jj] = (short)f2bf(w2);
    }
  }
  const float bias_c = okc ? ca1bias[col] : 0.f;
  const float cL = okc ? cueL[col] : 0.f;
  const float cR = okc ? cueR[col] : 0.f;

  __syncthreads();  // frag zero complete before state writes

  // --- fp32 state in registers (lane owns (r=q*4+i, col) — never shared) ---
  float ec3v[4], ec5v[4], c1[4] = {0.f,0.f,0.f,0.f};
  #pragma unroll
  for (int i = 0; i < 4; ++i){
    int r = q * 4 + i;
    float v3 = okc ? ec3_last[(size_t)(b0 + r) * ECN + col] : 0.f;
    float v5 = okc ? ec5_last[(size_t)(b0 + r) * ECN + col] : 0.f;
    ec3v[i] = v3; ec5v[i] = v5;
    if (okc) ec3b[abase + i * 8] = f2bf(v3);
  }
  __syncthreads();

  // running pointers
  const float* dp = drive + colc;                                   // += CA1N per step
  float* hp = out_his + (size_t)(b0 + q * 4) * CA1N + colc;         // += BSZ*CA1N per step

  const bf16x8* fe3 = (const bf16x8*)ec3b;   // chunk ks at index ks*64+lane
  const bf16x8* fc1 = (const bf16x8*)ca1b;

  float dv = *dp;                       // prefetched drive value for step t

  for (int t = 0; t < TLEN; ++t){
    int cu4 = *(const int*)(cueT + t * BT + q * 4);            // 4 cue bytes (rows q*4..)

    // ---- phase 1: z = ec3 @ W1 ; ca1 = relu(dv*(1+sig(z)) - bias) ----
    {
      bf16x8 a0 = fe3[  0 + lane];
      bf16x8 a1 = fe3[ 64 + lane];
      bf16x8 a2 = fe3[128 + lane];
      bf16x8 a3 = fe3[192 + lane];
      f32x4 aA = {0.f,0.f,0.f,0.f}, aB = {0.f,0.f,0.f,0.f};
      aA = __builtin_amdgcn_mfma_f32_16x16x32_bf16(a0, b1[0], aA, 0, 0, 0);
      aB = __builtin_amdgcn_mfma_f32_16x16x32_bf16(a1, b1[1], aB, 0, 0, 0);
      aA = __builtin_amdgcn_mfma_f32_16x16x32_bf16(a2, b1[2], aA, 0, 0, 0);
      aB = __builtin_amdgcn_mfma_f32_16x16x32_bf16(a3, b1[3], aB, 0, 0, 0);
      f32x4 z = aA + aB;
      float dmb = dv - bias_c;
      #pragma unroll
      for (int i = 0; i < 4; ++i){
        float v = fmaxf(fmaf(dv, fsigm(z[i]), dmb), 0.f);
        c1[i] = v;
        if (okc) ca1b[abase + i * 8] = f2bf(v);
      }
    }
    BAR_LGKM();

    // out_his stores after the barrier: no vmcnt drain at loop barriers,
    // they stay in flight under phase-2 compute.
    if (okc){
      hp[0 * CA1N] = c1[0];
      hp[1 * CA1N] = c1[1];
      hp[2 * CA1N] = c1[2];
      hp[3 * CA1N] = c1[3];
    }
    hp += (size_t)BSZ * CA1N;

    // prefetch next step's drive value (floats across the phase-2 barrier)
    dp += CA1N;
    float dv_next = (t + 1 < TLEN) ? *dp : 0.f;

    // ---- phase 2: z2 = ca1 @ W2 ; ec5/ec3 register update ----
    {
      bf16x8 a0 = fc1[  0 + lane];
      bf16x8 a1 = fc1[ 64 + lane];
      bf16x8 a2 = fc1[128 + lane];
      bf16x8 a3 = fc1[192 + lane];
      f32x4 aA = {0.f,0.f,0.f,0.f}, aB = {0.f,0.f,0.f,0.f};
      aA = __builtin_amdgcn_mfma_f32_16x16x32_bf16(a0, b2[0], aA, 0, 0, 0);
      aB = __builtin_amdgcn_mfma_f32_16x16x32_bf16(a1, b2[1], aB, 0, 0, 0);
      aA = __builtin_amdgcn_mfma_f32_16x16x32_bf16(a2, b2[2], aA, 0, 0, 0);
      aB = __builtin_amdgcn_mfma_f32_16x16x32_bf16(a3, b2[3], aB, 0, 0, 0);
      f32x4 z2 = aA + aB;
      #pragma unroll
      for (int i = 0; i < 4; ++i){
        float x  = ec5v[i] + z2[i];
        float e5 = fmaf(0.3f, fsigm(fmaf(4.0f, x, -1.2f)), 0.69f);
        ec5v[i] = e5;
        int cu = (cu4 >> (8 * i)) & 0xff;                 // -1 -> 0xff
        float sns = (cu == 1) ? cL : ((cu == 0xff) ? cR : 0.0f);
        float e3 = fmaf(e5, ec3v[i], sns);
        ec3v[i] = e3;
        if (okc) ec3b[abase + i * 8] = f2bf(e3);
      }
    }
    BAR_LGKM();
    dv = dv_next;
  }

  // ---- epilogue: dump final states from registers ----
  if (okc){
    #pragma unroll
    for (int i = 0; i < 4; ++i){
      int r = q * 4 + i;
      size_t g = (size_t)(b0 + r) * ECN + col;
      out_e3[g] = ec3v[i];
      out_e5[g] = ec5v[i];
      out_c1[g] = c1[i];
      ca1f[r * 132 + col] = c1[i];
    }
  }
  __syncthreads();

  // actCell = ca1_final @ Wca1act
  if (tid < BT * ACTN){
    int r = tid >> 1, a = tid & 1;
    float acc = 0.f;
    for (int jj = 0; jj < CA1N; ++jj)
      acc = fmaf(ca1f[r * 132 + jj], Wca1act[jj * ACTN + a], acc);
    out_act[(size_t)(b0 + r) * ACTN + a] = acc;
  }
}

extern "C" void kernel_launch(void* const* d_in, const int* in_sizes, int n_in,
                              void* d_out, int out_size, void* d_ws, size_t ws_size,
                              hipStream_t stream) {
  (void)in_sizes; (void)n_in; (void)out_size; (void)ws_size;
  const int*   cue_train = (const int*)  d_in[1];
  const float* ec3_last  = (const float*)d_in[2];
  const float* ec5_last  = (const float*)d_in[3];
  const float* cueL      = (const float*)d_in[5];
  const float* cueR      = (const float*)d_in[6];
  const float* Wec3ca1   = (const float*)d_in[7];
  const float* Wca3ca1   = (const float*)d_in[8];
  const float* Wca1ec5   = (const float*)d_in[9];
  const float* Wca1act   = (const float*)d_in[10];
  const float* ca1bias   = (const float*)d_in[11];
  float* out   = (float*)d_out;
  float* drive = (float*)d_ws;   // 100*100 fp32 = 40 KB scratch

  drive_kernel<<<TLEN, 128, 0, stream>>>(Wca3ca1, drive);
  rnn_kernel<<<BSZ / BT, NTHR, 0, stream>>>(cue_train, ec3_last, ec5_last,
                                            cueL, cueR, Wec3ca1, Wca1ec5,
                                            Wca1act, ca1bias, drive, out);
}